// Round 2
// baseline (243.351 us; speedup 1.0000x reference)
//
#include <hip/hip_runtime.h>
#include <hip/hip_bf16.h>
#include <math.h>

#define LQ_  2048
#define LK_  2048
#define D_   128
#define B_   16
#define LN_EPS 1e-5f
#define TK_  32
#define NTILE (LK_ / TK_)

// Pre-converted tile images in workspace:
#define KH_TILE_US 4096          // 32 rows x 128 d ushort (8192 B)
#define VT_TILE_U  2048          // 128 d x 16 slot uint (8192 B)
#define KH_BYTES   ((size_t)B_ * NTILE * KH_TILE_US * 2)   // 8,388,608
#define VT_OFF     (2 * KH_BYTES)                           // 16,777,216
// total ws: 25,165,824 B

typedef __attribute__((ext_vector_type(8))) short short8;
typedef __attribute__((ext_vector_type(4))) float f32x4;

union FragU { uint4 u4; short8 s8; unsigned int u[4]; };

__device__ __forceinline__ unsigned int pk_bf16(float a, float b) {
  __hip_bfloat162 h = __float22bfloat162_rn(make_float2(a, b));
  unsigned int u;
  __builtin_memcpy(&u, &h, 4);
  return u;
}
__device__ __forceinline__ float bf_lo(unsigned int u){ unsigned int v = u << 16; float f; __builtin_memcpy(&f, &v, 4); return f; }
__device__ __forceinline__ float bf_hi(unsigned int u){ unsigned int v = u & 0xffff0000u; float f; __builtin_memcpy(&f, &v, 4); return f; }
__device__ __forceinline__ unsigned short bf16_bits(float x) {
  return (unsigned short)(pk_bf16(x, 0.f) & 0xffffu);
}

// K tiles: ushort [32 rows][128 d], 16B(8-ushort)-chunk XOR swizzle by row.
__device__ __forceinline__ int idxK(int row, int d) {
  return row * 128 + ((((d >> 3) ^ row) & 15) << 3) + (d & 7);
}
// Vt: uint [128 d][16 kp-slots]; 16B chunk g' = (g + (d>>1)) & 3.
// Read pattern (lr over 16 d, quad over 4 g): each bank hit exactly 2x
// per 16-lane group -> conflict-free (2-way is free, m136).
__device__ __forceinline__ int idxVt(int d, int kp) {
  return d * 16 + ((((kp >> 2) + (d >> 1)) & 3) << 2) + (kp & 3);
}
// Ps: ushort [64 rows][32 cols], 8-ushort-chunk swizzle by quad bits of row.
__device__ __forceinline__ int idxPs(int row, int col) {
  return row * 32 + ((((col >> 3) ^ (row >> 2)) & 3) << 3) + (col & 7);
}

// LDS-only barrier: drains ds ops, leaves global (vmcnt) loads in flight.
__device__ __forceinline__ void barrier_lds() {
  asm volatile("s_waitcnt lgkmcnt(0)\n\ts_barrier" ::: "memory");
}
// Barrier that additionally drains this wave's tile-stage DMA; the 8 newest
// vm ops (the prefetched mask loads) stay in flight.
__device__ __forceinline__ void barrier_stage() {
  asm volatile("s_waitcnt vmcnt(8) lgkmcnt(0)\n\ts_barrier" ::: "memory");
}

__device__ __forceinline__ void gld_lds16(const void* g, void* l) {
  __builtin_amdgcn_global_load_lds((const __attribute__((address_space(1))) void*)g,
                                   (__attribute__((address_space(3))) void*)l, 16, 0, 0);
}

// ---------------- pre-pass: K -> (Khi,Klo) bf16 swizzled, V -> bf16-pair Vt ----
__global__ __launch_bounds__(256) void conv_kv(
    const float* __restrict__ kg, const float* __restrict__ vg,
    unsigned short* __restrict__ khg, unsigned short* __restrict__ klg,
    unsigned int* __restrict__ vtg)
{
  __shared__ float Vlt[128 * 33];   // V tile transposed, +1-pad rows
  const int tid = threadIdx.x;
  const int blk = blockIdx.x;          // b*64 + t
  const int b = blk >> 6;
  const int t = blk & 63;

  const float* ks = kg + ((size_t)b * LK_ + t * 32) * D_;
  const float* vs = vg + ((size_t)b * LK_ + t * 32) * D_;
  unsigned short* kh = khg + (size_t)blk * KH_TILE_US;
  unsigned short* kl = klg + (size_t)blk * KH_TILE_US;
  unsigned int*   vt = vtg + (size_t)blk * VT_TILE_U;

  // K: 512 (row, 8-chunk) items, 2 per thread; coalesced reads, 16B swizzled writes
#pragma unroll
  for (int it = 0; it < 2; it++) {
    const int item = tid + it * 256;
    const int row = item >> 4;
    const int c8  = item & 15;
    const float* p = ks + row * D_ + c8 * 8;
    float4 x = *(const float4*)(p);
    float4 y = *(const float4*)(p + 4);
    FragU H, L;
    H.u[0] = pk_bf16(x.x, x.y); H.u[1] = pk_bf16(x.z, x.w);
    H.u[2] = pk_bf16(y.x, y.y); H.u[3] = pk_bf16(y.z, y.w);
    L.u[0] = pk_bf16(x.x - bf_lo(H.u[0]), x.y - bf_hi(H.u[0]));
    L.u[1] = pk_bf16(x.z - bf_lo(H.u[1]), x.w - bf_hi(H.u[1]));
    L.u[2] = pk_bf16(y.x - bf_lo(H.u[2]), y.y - bf_hi(H.u[2]));
    L.u[3] = pk_bf16(y.z - bf_lo(H.u[3]), y.w - bf_hi(H.u[3]));
    const int ik = idxK(row, c8 * 8);
    *(uint4*)&kh[ik] = H.u4;
    *(uint4*)&kl[ik] = L.u4;
  }

  // V tile -> LDS transposed (coalesced global reads; ~4-way LDS write
  // conflicts, but column reads in the emit pass become conflict-free).
#pragma unroll
  for (int i = 0; i < 4; i++) {
    const int item = tid + i * 256;
    const int r = item >> 5, c4 = item & 31;
    float4 x = *(const float4*)&vs[r * D_ + c4 * 4];
    Vlt[(c4 * 4 + 0) * 33 + r] = x.x;
    Vlt[(c4 * 4 + 1) * 33 + r] = x.y;
    Vlt[(c4 * 4 + 2) * 33 + r] = x.z;
    Vlt[(c4 * 4 + 3) * 33 + r] = x.w;
  }
  __syncthreads();

  // Emit Vt image linearly (coalesced writes); inverse-map slot -> kv pair.
#pragma unroll
  for (int i = 0; i < 8; i++) {
    const int o = tid + i * 256;
    const int d = o >> 4, s = o & 15;
    const int gq = s >> 2, c = s & 3;
    const int kp = (((gq - (d >> 1)) & 3) << 2) | c;
    vt[o] = pk_bf16(Vlt[d * 33 + 2 * kp], Vlt[d * 33 + 2 * kp + 1]);
  }
}

// ---------------- main fused attention + LN ----------------
// Stage one tile's images into LDS buffers via global_load_lds.
// Exactly 6 x 1KiB 16B-wide ops per wave (uniform -> counted vmcnt works).
__device__ __forceinline__ void stage_tile(int w, int lane,
    const unsigned short* khT, const unsigned short* klT, const unsigned int* vtT,
    int tile, unsigned short* khs, unsigned short* kls, unsigned int* vts)
{
  const char* gkh = (const char*)(khT + (size_t)tile * KH_TILE_US);
  const char* gkl = (const char*)(klT + (size_t)tile * KH_TILE_US);
  const char* gvt = (const char*)(vtT + (size_t)tile * VT_TILE_U);
#pragma unroll
  for (int c = 0; c < 2; c++) {
    const int off = (w + 4 * c) << 10;            // 1 KiB chunks
    gld_lds16(gkh + off + lane * 16, (char*)khs + off);
    gld_lds16(gkl + off + lane * 16, (char*)kls + off);
    gld_lds16(gvt + off + lane * 16, (char*)vts + off);
  }
}

__global__ __launch_bounds__(256, 3) void attn_ln_mfma(
    const float* __restrict__ qg, const float* __restrict__ maskg,
    const float* __restrict__ gammag, const float* __restrict__ betag,
    const unsigned short* __restrict__ khg, const unsigned short* __restrict__ klg,
    const unsigned int* __restrict__ vtg,
    float* __restrict__ outg)
{
  __shared__ unsigned short KhS[2][32 * 128];   // 16 KB
  __shared__ unsigned short KlS[2][32 * 128];   // 16 KB
  __shared__ unsigned int   VtW[2][128 * 16];   // 16 KB
  __shared__ unsigned short PsS[64 * 32];       // 4 KB; epilogue reuses as exch
  // total 53,248 B -> 3 blocks/CU capacity

  float* lExch = (float*)&PsS[0];               // 128 floats
  float* sExch = ((float*)&PsS[0]) + 128;       // 256 floats

  const int tid  = threadIdx.x;
  const int w    = tid >> 6;
  const int lane = tid & 63;
  const int quad = lane >> 4;
  const int lr   = lane & 15;
  const int rowgrp = w & 1;     // q-rows rowgrp*32 .. +32
  const int khalf  = w >> 1;    // QK: k-cols khalf*16..+16; PV: d-cols khalf*64..+64

  // XCD swizzle: blocks on XCD x serve batches {2x,2x+1} -> K/V L2-resident.
  const int id   = blockIdx.x;
  const int xcd  = id & 7;
  const int slot = id >> 3;
  const int b    = xcd * 2 + (slot >> 5);
  const int q0   = (slot & 31) * 64;

  const unsigned short* khT = khg + (size_t)b * NTILE * KH_TILE_US;
  const unsigned short* klT = klg + (size_t)b * NTILE * KH_TILE_US;
  const unsigned int*   vtT = vtg + (size_t)b * NTILE * VT_TILE_U;

  const float* mbase = maskg + (size_t)(q0 + rowgrp * 32 + quad * 4) * LK_ + khalf * 16 + lr;

  // ---- issue tile-0 stage DMA + mask(0) prefetch (fly during Q-frag build) ----
  stage_tile(w, lane, khT, klT, vtT, 0, &KhS[0][0], &KlS[0][0], &VtW[0][0]);
  float mcur[2][4];
#pragma unroll
  for (int rt = 0; rt < 2; rt++)
#pragma unroll
    for (int reg = 0; reg < 4; reg++)
      mcur[rt][reg] = mbase[(size_t)(rt * 16 + reg) * LK_];

  // ---- Q fragments (hi/lo) for 32 rows (2 rt), registers for whole loop ----
  short8 qh[2][4], ql[2][4];
#pragma unroll
  for (int rt = 0; rt < 2; rt++) {
    const float* qrow = qg + ((size_t)b * LQ_ + q0 + rowgrp * 32 + rt * 16 + lr) * D_ + quad * 8;
#pragma unroll
    for (int c = 0; c < 4; c++) {
      float4 x = *(const float4*)(qrow + c * 32);
      float4 y = *(const float4*)(qrow + c * 32 + 4);
      FragU H, L;
      H.u[0] = pk_bf16(x.x, x.y); H.u[1] = pk_bf16(x.z, x.w);
      H.u[2] = pk_bf16(y.x, y.y); H.u[3] = pk_bf16(y.z, y.w);
      L.u[0] = pk_bf16(x.x - bf_lo(H.u[0]), x.y - bf_hi(H.u[0]));
      L.u[1] = pk_bf16(x.z - bf_lo(H.u[1]), x.w - bf_hi(H.u[1]));
      L.u[2] = pk_bf16(y.x - bf_lo(H.u[2]), y.y - bf_hi(H.u[2]));
      L.u[3] = pk_bf16(y.z - bf_lo(H.u[3]), y.w - bf_hi(H.u[3]));
      qh[rt][c] = H.s8; ql[rt][c] = L.s8;
    }
  }

  float l_part[2][4];
  f32x4 o[2][4];                 // [rt][nb]: d = khalf*64 + nb*16 + lr
  const f32x4 zf = {0.f, 0.f, 0.f, 0.f};
#pragma unroll
  for (int rt = 0; rt < 2; rt++) {
#pragma unroll
    for (int r = 0; r < 4; r++) l_part[rt][r] = 0.f;
#pragma unroll
    for (int n = 0; n < 4; n++) o[rt][n] = zf;
  }

  for (int kt = 0; kt < NTILE; kt++) {
    const int cur = kt & 1;
    const unsigned short* khc = &KhS[cur][0];
    const unsigned short* klc = &KlS[cur][0];
    const unsigned int*   vtc = &VtW[cur][0];

    // stage(cur) DMA complete in this wave + all waves past prev PV reads;
    // mask(kt) loads (the 8 newest vm ops) stay in flight.
    barrier_stage();

    // ---- issue NEXT tile stage (6 vm) + NEXT mask prefetch (8 vm) ----
    float mnext[2][4];
    if (kt + 1 < NTILE) {
      stage_tile(w, lane, khT, klT, vtT, kt + 1,
                 &KhS[cur ^ 1][0], &KlS[cur ^ 1][0], &VtW[cur ^ 1][0]);
#pragma unroll
      for (int rt = 0; rt < 2; rt++)
#pragma unroll
        for (int reg = 0; reg < 4; reg++)
          mnext[rt][reg] = mbase[(size_t)(rt * 16 + reg) * LK_ + (kt + 1) * TK_];
    }

    // ---- S = Q K^T via MFMA (hi/lo); this wave: 32 rows x 16 k-cols ----
    f32x4 sacc[2];
    sacc[0] = zf; sacc[1] = zf;
#pragma unroll
    for (int c = 0; c < 4; c++) {
      const int kb = c * 32 + quad * 8;
      const int krow = khalf * 16 + lr;
      FragU kh, kl;
      kh.u4 = *(const uint4*)&khc[idxK(krow, kb)];
      kl.u4 = *(const uint4*)&klc[idxK(krow, kb)];
#pragma unroll
      for (int rt = 0; rt < 2; rt++) {
        sacc[rt] = __builtin_amdgcn_mfma_f32_16x16x32_bf16(qh[rt][c], kh.s8, sacc[rt], 0, 0, 0);
        sacc[rt] = __builtin_amdgcn_mfma_f32_16x16x32_bf16(ql[rt][c], kh.s8, sacc[rt], 0, 0, 0);
        sacc[rt] = __builtin_amdgcn_mfma_f32_16x16x32_bf16(qh[rt][c], kl.s8, sacc[rt], 0, 0, 0);
      }
    }

    // ---- hoist Bv (Vt) reads: LDS latency overlaps the exp chain ----
    FragU Bv[4];
#pragma unroll
    for (int nb = 0; nb < 4; nb++)
      Bv[nb].u4 = *(const uint4*)&vtc[idxVt(khalf * 64 + nb * 16 + lr, quad * 4)];

    // ---- max-free softmax (mask from registers); P -> LDS as bf16 ----
#pragma unroll
    for (int rt = 0; rt < 2; rt++)
#pragma unroll
      for (int reg = 0; reg < 4; reg++) {
        float p = __expf(sacc[rt][reg] + mcur[rt][reg]);
        l_part[rt][reg] += p;
        PsS[idxPs(rowgrp * 32 + rt * 16 + quad * 4 + reg, khalf * 16 + lr)] = bf16_bits(p);
      }

    barrier_lds();   // all waves' Ps visible (PV reads both k-halves)

    // ---- O += P * V via MFMA; this wave: 32 rows x 64 d-cols, full 32 k ----
#pragma unroll
    for (int rt = 0; rt < 2; rt++) {
      FragU A;
      A.u4 = *(const uint4*)&PsS[idxPs(rowgrp * 32 + rt * 16 + lr, quad * 8)];
#pragma unroll
      for (int nb = 0; nb < 4; nb++)
        o[rt][nb] = __builtin_amdgcn_mfma_f32_16x16x32_bf16(A.s8, Bv[nb].s8, o[rt][nb], 0, 0, 0);
    }

    if (kt + 1 < NTILE) {
#pragma unroll
      for (int rt = 0; rt < 2; rt++)
#pragma unroll
        for (int reg = 0; reg < 4; reg++)
          mcur[rt][reg] = mnext[rt][reg];
    }
  }

  // ---- epilogue ----
  barrier_lds();   // all waves done with PsS (it is reused as exch below)

  // 1) total l per row: reduce over 16 lanes, exchange k-halves via LDS.
  float lred[2][4];
#pragma unroll
  for (int rt = 0; rt < 2; rt++)
#pragma unroll
    for (int reg = 0; reg < 4; reg++) {
      float l = l_part[rt][reg];
#pragma unroll
      for (int m = 1; m <= 8; m <<= 1) l += __shfl_xor(l, m, 64);
      lred[rt][reg] = l;
    }
  if (lr == 0) {
#pragma unroll
    for (int rt = 0; rt < 2; rt++)
#pragma unroll
      for (int reg = 0; reg < 4; reg++)
        lExch[khalf * 64 + rowgrp * 32 + rt * 16 + quad * 4 + reg] = lred[rt][reg];
  }
  barrier_lds();

  float inv_l[2][4];
#pragma unroll
  for (int rt = 0; rt < 2; rt++)
#pragma unroll
    for (int reg = 0; reg < 4; reg++) {
      const int row = rowgrp * 32 + rt * 16 + quad * 4 + reg;
      inv_l[rt][reg] = 1.f / (lred[rt][reg] + lExch[(1 ^ khalf) * 64 + row]);
    }

  // 2) normalize O, compute partial LN moments over this wave's 64 d-cols.
  float s1p[2][4], s2p[2][4];
#pragma unroll
  for (int rt = 0; rt < 2; rt++)
#pragma unroll
    for (int reg = 0; reg < 4; reg++) {
      float s1 = 0.f, s2 = 0.f;
#pragma unroll
      for (int nb = 0; nb < 4; nb++) {
        float v = o[rt][nb][reg] * inv_l[rt][reg];
        o[rt][nb][reg] = v;
        s1 += v; s2 += v * v;
      }
#pragma unroll
      for (int m = 1; m <= 8; m <<= 1) {
        s1 += __shfl_xor(s1, m, 64);
        s2 += __shfl_xor(s2, m, 64);
      }
      s1p[rt][reg] = s1; s2p[rt][reg] = s2;
    }
  if (lr == 0) {
#pragma unroll
    for (int rt = 0; rt < 2; rt++)
#pragma unroll
      for (int reg = 0; reg < 4; reg++) {
        const int row = rowgrp * 32 + rt * 16 + quad * 4 + reg;
        sExch[(khalf * 64 + row) * 2 + 0] = s1p[rt][reg];
        sExch[(khalf * 64 + row) * 2 + 1] = s2p[rt][reg];
      }
  }
  barrier_lds();

  // 3) gamma/beta for this wave's d-cols, final LN, store.
  float gam[4], bet[4];
#pragma unroll
  for (int nb = 0; nb < 4; nb++) {
    gam[nb] = gammag[khalf * 64 + nb * 16 + lr];
    bet[nb] = betag[khalf * 64 + nb * 16 + lr];
  }

#pragma unroll
  for (int rt = 0; rt < 2; rt++)
#pragma unroll
    for (int reg = 0; reg < 4; reg++) {
      const int row = rowgrp * 32 + rt * 16 + quad * 4 + reg;
      const float s1 = s1p[rt][reg] + sExch[((1 ^ khalf) * 64 + row) * 2 + 0];
      const float s2 = s2p[rt][reg] + sExch[((1 ^ khalf) * 64 + row) * 2 + 1];
      const float mean = s1 * (1.f / 128.f);
      const float var  = s2 * (1.f / 128.f) - mean * mean;
      const float rstd = rsqrtf(var + LN_EPS);

      float* op = outg + ((size_t)b * LQ_ + q0 + row) * D_ + khalf * 64 + lr;
#pragma unroll
      for (int nb = 0; nb < 4; nb++)
        op[nb * 16] = (o[rt][nb][reg] - mean) * rstd * gam[nb] + bet[nb];
    }
}

extern "C" void kernel_launch(void* const* d_in, const int* in_sizes, int n_in,
                              void* d_out, int out_size, void* d_ws, size_t ws_size,
                              hipStream_t stream) {
  const float* q     = (const float*)d_in[0];
  const float* k     = (const float*)d_in[1];
  const float* v     = (const float*)d_in[2];
  const float* mask  = (const float*)d_in[3];
  const float* gamma = (const float*)d_in[4];
  const float* beta  = (const float*)d_in[5];
  float* out = (float*)d_out;

  unsigned short* khg = (unsigned short*)d_ws;
  unsigned short* klg = (unsigned short*)((char*)d_ws + KH_BYTES);
  unsigned int*   vtg = (unsigned int*)((char*)d_ws + VT_OFF);

  conv_kv<<<dim3(B_ * NTILE), dim3(256), 0, stream>>>(k, v, khg, klg, vtg);
  attn_ln_mfma<<<dim3(512), dim3(256), 0, stream>>>(q, mask, gamma, beta,
                                                    khg, klg, vtg, out);
}

// Round 3
// 196.458 us; speedup vs baseline: 1.2387x; 1.2387x over previous
//
#include <hip/hip_runtime.h>
#include <hip/hip_bf16.h>
#include <math.h>

#define LQ_  2048
#define LK_  2048
#define D_   128
#define B_   16
#define LN_EPS 1e-5f
#define TK_  32
#define NTILE (LK_ / TK_)

// Pre-converted tile images in workspace:
#define KH_TILE_US 4096          // 32 rows x 128 d ushort (8192 B)
#define VT_TILE_U  2048          // 128 d x 16 slot uint (8192 B)
#define KH_BYTES   ((size_t)B_ * NTILE * KH_TILE_US * 2)   // 8,388,608
#define VT_OFF     (2 * KH_BYTES)                           // 16,777,216
// total ws: 25,165,824 B

typedef __attribute__((ext_vector_type(8))) short short8;
typedef __attribute__((ext_vector_type(4))) float f32x4;

union FragU { uint4 u4; short8 s8; unsigned int u[4]; };

__device__ __forceinline__ unsigned int pk_bf16(float a, float b) {
  __hip_bfloat162 h = __float22bfloat162_rn(make_float2(a, b));
  unsigned int u;
  __builtin_memcpy(&u, &h, 4);
  return u;
}
__device__ __forceinline__ float bf_lo(unsigned int u){ unsigned int v = u << 16; float f; __builtin_memcpy(&f, &v, 4); return f; }
__device__ __forceinline__ float bf_hi(unsigned int u){ unsigned int v = u & 0xffff0000u; float f; __builtin_memcpy(&f, &v, 4); return f; }
__device__ __forceinline__ unsigned short bf16_bits(float x) {
  return (unsigned short)(pk_bf16(x, 0.f) & 0xffffu);
}

// K tiles: ushort [32 rows][128 d], 16B(8-ushort)-chunk XOR swizzle by row.
__device__ __forceinline__ int idxK(int row, int d) {
  return row * 128 + ((((d >> 3) ^ row) & 15) << 3) + (d & 7);
}
// Vt: uint [128 d][16 kp-slots]; 16B chunk g' = (g + (d>>1)) & 3.
// Read pattern (lr over 16 d, quad over 4 g): each bank hit exactly 2x
// per 16-lane group -> conflict-free (2-way is free, m136).
__device__ __forceinline__ int idxVt(int d, int kp) {
  return d * 16 + ((((kp >> 2) + (d >> 1)) & 3) << 2) + (kp & 3);
}
// Ps: ushort [64 rows][32 cols], 8-ushort-chunk swizzle by quad bits of row.
__device__ __forceinline__ int idxPs(int row, int col) {
  return row * 32 + ((((col >> 3) ^ (row >> 2)) & 3) << 3) + (col & 7);
}

// LDS-only barrier: drains ds ops, leaves global (vmcnt) loads in flight.
__device__ __forceinline__ void barrier_lds() {
  asm volatile("s_waitcnt lgkmcnt(0)\n\ts_barrier" ::: "memory");
}
// Barrier that additionally drains this wave's tile-stage DMA; the 8 newest
// vm ops (the prefetched mask loads) stay in flight.
__device__ __forceinline__ void barrier_stage() {
  asm volatile("s_waitcnt vmcnt(8) lgkmcnt(0)\n\ts_barrier" ::: "memory");
}

__device__ __forceinline__ void gld_lds16(const void* g, void* l) {
  __builtin_amdgcn_global_load_lds((const __attribute__((address_space(1))) void*)g,
                                   (__attribute__((address_space(3))) void*)l, 16, 0, 0);
}

// ---------------- pre-pass: K -> (Khi,Klo) bf16 swizzled, V -> bf16-pair Vt ----
__global__ __launch_bounds__(256) void conv_kv(
    const float* __restrict__ kg, const float* __restrict__ vg,
    unsigned short* __restrict__ khg, unsigned short* __restrict__ klg,
    unsigned int* __restrict__ vtg)
{
  __shared__ float Vlt[128 * 33];   // V tile transposed, +1-pad rows
  const int tid = threadIdx.x;
  const int blk = blockIdx.x;          // b*64 + t
  const int b = blk >> 6;
  const int t = blk & 63;

  const float* ks = kg + ((size_t)b * LK_ + t * 32) * D_;
  const float* vs = vg + ((size_t)b * LK_ + t * 32) * D_;
  unsigned short* kh = khg + (size_t)blk * KH_TILE_US;
  unsigned short* kl = klg + (size_t)blk * KH_TILE_US;
  unsigned int*   vt = vtg + (size_t)blk * VT_TILE_U;

  // K: 512 (row, 8-chunk) items, 2 per thread; coalesced reads, 16B swizzled writes
#pragma unroll
  for (int it = 0; it < 2; it++) {
    const int item = tid + it * 256;
    const int row = item >> 4;
    const int c8  = item & 15;
    const float* p = ks + row * D_ + c8 * 8;
    float4 x = *(const float4*)(p);
    float4 y = *(const float4*)(p + 4);
    FragU H, L;
    H.u[0] = pk_bf16(x.x, x.y); H.u[1] = pk_bf16(x.z, x.w);
    H.u[2] = pk_bf16(y.x, y.y); H.u[3] = pk_bf16(y.z, y.w);
    L.u[0] = pk_bf16(x.x - bf_lo(H.u[0]), x.y - bf_hi(H.u[0]));
    L.u[1] = pk_bf16(x.z - bf_lo(H.u[1]), x.w - bf_hi(H.u[1]));
    L.u[2] = pk_bf16(y.x - bf_lo(H.u[2]), y.y - bf_hi(H.u[2]));
    L.u[3] = pk_bf16(y.z - bf_lo(H.u[3]), y.w - bf_hi(H.u[3]));
    const int ik = idxK(row, c8 * 8);
    *(uint4*)&kh[ik] = H.u4;
    *(uint4*)&kl[ik] = L.u4;
  }

  // V tile -> LDS transposed (coalesced global reads; ~4-way LDS write
  // conflicts, but column reads in the emit pass become conflict-free).
#pragma unroll
  for (int i = 0; i < 4; i++) {
    const int item = tid + i * 256;
    const int r = item >> 5, c4 = item & 31;
    float4 x = *(const float4*)&vs[r * D_ + c4 * 4];
    Vlt[(c4 * 4 + 0) * 33 + r] = x.x;
    Vlt[(c4 * 4 + 1) * 33 + r] = x.y;
    Vlt[(c4 * 4 + 2) * 33 + r] = x.z;
    Vlt[(c4 * 4 + 3) * 33 + r] = x.w;
  }
  __syncthreads();

  // Emit Vt image linearly (coalesced writes); inverse-map slot -> kv pair.
#pragma unroll
  for (int i = 0; i < 8; i++) {
    const int o = tid + i * 256;
    const int d = o >> 4, s = o & 15;
    const int gq = s >> 2, c = s & 3;
    const int kp = (((gq - (d >> 1)) & 3) << 2) | c;
    vt[o] = pk_bf16(Vlt[d * 33 + 2 * kp], Vlt[d * 33 + 2 * kp + 1]);
  }
}

// ---------------- main fused attention + LN ----------------
// Stage one tile's images into LDS buffers via global_load_lds.
// Exactly 6 x 1KiB 16B-wide ops per wave (uniform -> counted vmcnt works).
__device__ __forceinline__ void stage_tile(int w, int lane,
    const unsigned short* khT, const unsigned short* klT, const unsigned int* vtT,
    int tile, unsigned short* khs, unsigned short* kls, unsigned int* vts)
{
  const char* gkh = (const char*)(khT + (size_t)tile * KH_TILE_US);
  const char* gkl = (const char*)(klT + (size_t)tile * KH_TILE_US);
  const char* gvt = (const char*)(vtT + (size_t)tile * VT_TILE_U);
#pragma unroll
  for (int c = 0; c < 2; c++) {
    const int off = (w + 4 * c) << 10;            // 1 KiB chunks
    gld_lds16(gkh + off + lane * 16, (char*)khs + off);
    gld_lds16(gkl + off + lane * 16, (char*)kls + off);
    gld_lds16(gvt + off + lane * 16, (char*)vts + off);
  }
}

__global__ __launch_bounds__(256, 2) void attn_ln_mfma(
    const float* __restrict__ qg, const float* __restrict__ maskg,
    const float* __restrict__ gammag, const float* __restrict__ betag,
    const unsigned short* __restrict__ khg, const unsigned short* __restrict__ klg,
    const unsigned int* __restrict__ vtg,
    float* __restrict__ outg)
{
  __shared__ unsigned short KhS[2][32 * 128];   // 16 KB
  __shared__ unsigned short KlS[2][32 * 128];   // 16 KB
  __shared__ unsigned int   VtW[2][128 * 16];   // 16 KB
  __shared__ unsigned short PsS[64 * 32];       // 4 KB; epilogue reuses as exch
  // total 53,248 B

  float* lExch = (float*)&PsS[0];               // 128 floats
  float* sExch = ((float*)&PsS[0]) + 128;       // 256 floats

  const int tid  = threadIdx.x;
  const int w    = tid >> 6;
  const int lane = tid & 63;
  const int quad = lane >> 4;
  const int lr   = lane & 15;
  const int rowgrp = w & 1;     // q-rows rowgrp*32 .. +32
  const int khalf  = w >> 1;    // QK: k-cols khalf*16..+16; PV: d-cols khalf*64..+64

  // XCD swizzle: blocks on XCD x serve batches {2x,2x+1} -> K/V L2-resident.
  const int id   = blockIdx.x;
  const int xcd  = id & 7;
  const int slot = id >> 3;
  const int b    = xcd * 2 + (slot >> 5);
  const int q0   = (slot & 31) * 64;

  const unsigned short* khT = khg + (size_t)b * NTILE * KH_TILE_US;
  const unsigned short* klT = klg + (size_t)b * NTILE * KH_TILE_US;
  const unsigned int*   vtT = vtg + (size_t)b * NTILE * VT_TILE_U;

  const float* mbase = maskg + (size_t)(q0 + rowgrp * 32 + quad * 4) * LK_ + khalf * 16 + lr;

  // ---- issue tile-0 stage DMA + mask(0) prefetch (fly during Q-frag build) ----
  stage_tile(w, lane, khT, klT, vtT, 0, &KhS[0][0], &KlS[0][0], &VtW[0][0]);
  float mA[2][4], mB[2][4];
#pragma unroll
  for (int rt = 0; rt < 2; rt++)
#pragma unroll
    for (int reg = 0; reg < 4; reg++)
      mA[rt][reg] = mbase[(size_t)(rt * 16 + reg) * LK_];

  // ---- Q fragments (hi/lo) for 32 rows (2 rt), registers for whole loop ----
  short8 qh[2][4], ql[2][4];
#pragma unroll
  for (int rt = 0; rt < 2; rt++) {
    const float* qrow = qg + ((size_t)b * LQ_ + q0 + rowgrp * 32 + rt * 16 + lr) * D_ + quad * 8;
#pragma unroll
    for (int c = 0; c < 4; c++) {
      float4 x = *(const float4*)(qrow + c * 32);
      float4 y = *(const float4*)(qrow + c * 32 + 4);
      FragU H, L;
      H.u[0] = pk_bf16(x.x, x.y); H.u[1] = pk_bf16(x.z, x.w);
      H.u[2] = pk_bf16(y.x, y.y); H.u[3] = pk_bf16(y.z, y.w);
      L.u[0] = pk_bf16(x.x - bf_lo(H.u[0]), x.y - bf_hi(H.u[0]));
      L.u[1] = pk_bf16(x.z - bf_lo(H.u[1]), x.w - bf_hi(H.u[1]));
      L.u[2] = pk_bf16(y.x - bf_lo(H.u[2]), y.y - bf_hi(H.u[2]));
      L.u[3] = pk_bf16(y.z - bf_lo(H.u[3]), y.w - bf_hi(H.u[3]));
      qh[rt][c] = H.s8; ql[rt][c] = L.s8;
    }
  }

  float l_part[2][4];
  f32x4 o[2][4];                 // [rt][nb]: d = khalf*64 + nb*16 + lr
  const f32x4 zf = {0.f, 0.f, 0.f, 0.f};
#pragma unroll
  for (int rt = 0; rt < 2; rt++) {
#pragma unroll
    for (int r = 0; r < 4; r++) l_part[rt][r] = 0.f;
#pragma unroll
    for (int n = 0; n < 4; n++) o[rt][n] = zf;
  }

  // One tile body. cur is a literal (0/1); mu holds mask(kt); mask(kt+1) is
  // prefetched into mp (named registers, no copies -> counted vmcnt at use).
  auto body = [&](int kt, int cur, float (&mu)[2][4], float (&mp)[2][4])
      __attribute__((always_inline)) -> void {
    const unsigned short* khc = &KhS[cur][0];
    const unsigned short* klc = &KlS[cur][0];
    const unsigned int*   vtc = &VtW[cur][0];

    // stage(kt) DMA complete in this wave + all waves past prev PV reads;
    // mask(kt) loads (the 8 newest vm ops) stay in flight.
    barrier_stage();

    // ---- issue NEXT tile stage (6 vm) + NEXT mask prefetch (8 vm) ----
    if (kt + 1 < NTILE) {
      stage_tile(w, lane, khT, klT, vtT, kt + 1,
                 &KhS[cur ^ 1][0], &KlS[cur ^ 1][0], &VtW[cur ^ 1][0]);
#pragma unroll
      for (int rt = 0; rt < 2; rt++)
#pragma unroll
        for (int reg = 0; reg < 4; reg++)
          mp[rt][reg] = mbase[(size_t)(rt * 16 + reg) * LK_ + (kt + 1) * TK_];
    }

    // ---- S = Q K^T via MFMA (hi/lo); this wave: 32 rows x 16 k-cols ----
    f32x4 sacc[2];
    sacc[0] = zf; sacc[1] = zf;
#pragma unroll
    for (int c = 0; c < 4; c++) {
      const int kb = c * 32 + quad * 8;
      const int krow = khalf * 16 + lr;
      FragU kh, kl;
      kh.u4 = *(const uint4*)&khc[idxK(krow, kb)];
      kl.u4 = *(const uint4*)&klc[idxK(krow, kb)];
#pragma unroll
      for (int rt = 0; rt < 2; rt++) {
        sacc[rt] = __builtin_amdgcn_mfma_f32_16x16x32_bf16(qh[rt][c], kh.s8, sacc[rt], 0, 0, 0);
        sacc[rt] = __builtin_amdgcn_mfma_f32_16x16x32_bf16(ql[rt][c], kh.s8, sacc[rt], 0, 0, 0);
        sacc[rt] = __builtin_amdgcn_mfma_f32_16x16x32_bf16(qh[rt][c], kl.s8, sacc[rt], 0, 0, 0);
      }
    }

    // ---- hoist Bv (Vt) reads: LDS latency overlaps the exp chain ----
    FragU Bv[4];
#pragma unroll
    for (int nb = 0; nb < 4; nb++)
      Bv[nb].u4 = *(const uint4*)&vtc[idxVt(khalf * 64 + nb * 16 + lr, quad * 4)];

    // ---- max-free softmax (mask from registers); P -> LDS as bf16 ----
#pragma unroll
    for (int rt = 0; rt < 2; rt++)
#pragma unroll
      for (int reg = 0; reg < 4; reg++) {
        float p = __expf(sacc[rt][reg] + mu[rt][reg]);
        l_part[rt][reg] += p;
        PsS[idxPs(rowgrp * 32 + rt * 16 + quad * 4 + reg, khalf * 16 + lr)] = bf16_bits(p);
      }

    barrier_lds();   // all waves' Ps visible (PV reads both k-halves)

    // ---- O += P * V via MFMA; this wave: 32 rows x 64 d-cols, full 32 k ----
#pragma unroll
    for (int rt = 0; rt < 2; rt++) {
      FragU A;
      A.u4 = *(const uint4*)&PsS[idxPs(rowgrp * 32 + rt * 16 + lr, quad * 8)];
#pragma unroll
      for (int nb = 0; nb < 4; nb++)
        o[rt][nb] = __builtin_amdgcn_mfma_f32_16x16x32_bf16(A.s8, Bv[nb].s8, o[rt][nb], 0, 0, 0);
    }
  };

  for (int kt = 0; kt < NTILE; kt += 2) {
    body(kt,     0, mA, mB);   // consumes mask in mA, prefetches into mB
    body(kt + 1, 1, mB, mA);   // consumes mask in mB, prefetches into mA
  }

  // ---- epilogue ----
  barrier_lds();   // all waves done with PsS (it is reused as exch below)

  // 1) total l per row: reduce over 16 lanes, exchange k-halves via LDS.
  float lred[2][4];
#pragma unroll
  for (int rt = 0; rt < 2; rt++)
#pragma unroll
    for (int reg = 0; reg < 4; reg++) {
      float l = l_part[rt][reg];
#pragma unroll
      for (int m = 1; m <= 8; m <<= 1) l += __shfl_xor(l, m, 64);
      lred[rt][reg] = l;
    }
  if (lr == 0) {
#pragma unroll
    for (int rt = 0; rt < 2; rt++)
#pragma unroll
      for (int reg = 0; reg < 4; reg++)
        lExch[khalf * 64 + rowgrp * 32 + rt * 16 + quad * 4 + reg] = lred[rt][reg];
  }
  barrier_lds();

  float inv_l[2][4];
#pragma unroll
  for (int rt = 0; rt < 2; rt++)
#pragma unroll
    for (int reg = 0; reg < 4; reg++) {
      const int row = rowgrp * 32 + rt * 16 + quad * 4 + reg;
      inv_l[rt][reg] = 1.f / (lred[rt][reg] + lExch[(1 ^ khalf) * 64 + row]);
    }

  // 2) normalize O, compute partial LN moments over this wave's 64 d-cols.
  float s1p[2][4], s2p[2][4];
#pragma unroll
  for (int rt = 0; rt < 2; rt++)
#pragma unroll
    for (int reg = 0; reg < 4; reg++) {
      float s1 = 0.f, s2 = 0.f;
#pragma unroll
      for (int nb = 0; nb < 4; nb++) {
        float v = o[rt][nb][reg] * inv_l[rt][reg];
        o[rt][nb][reg] = v;
        s1 += v; s2 += v * v;
      }
#pragma unroll
      for (int m = 1; m <= 8; m <<= 1) {
        s1 += __shfl_xor(s1, m, 64);
        s2 += __shfl_xor(s2, m, 64);
      }
      s1p[rt][reg] = s1; s2p[rt][reg] = s2;
    }
  if (lr == 0) {
#pragma unroll
    for (int rt = 0; rt < 2; rt++)
#pragma unroll
      for (int reg = 0; reg < 4; reg++) {
        const int row = rowgrp * 32 + rt * 16 + quad * 4 + reg;
        sExch[(khalf * 64 + row) * 2 + 0] = s1p[rt][reg];
        sExch[(khalf * 64 + row) * 2 + 1] = s2p[rt][reg];
      }
  }
  barrier_lds();

  // 3) gamma/beta for this wave's d-cols, final LN, store.
  float gam[4], bet[4];
#pragma unroll
  for (int nb = 0; nb < 4; nb++) {
    gam[nb] = gammag[khalf * 64 + nb * 16 + lr];
    bet[nb] = betag[khalf * 64 + nb * 16 + lr];
  }

#pragma unroll
  for (int rt = 0; rt < 2; rt++)
#pragma unroll
    for (int reg = 0; reg < 4; reg++) {
      const int row = rowgrp * 32 + rt * 16 + quad * 4 + reg;
      const float s1 = s1p[rt][reg] + sExch[((1 ^ khalf) * 64 + row) * 2 + 0];
      const float s2 = s2p[rt][reg] + sExch[((1 ^ khalf) * 64 + row) * 2 + 1];
      const float mean = s1 * (1.f / 128.f);
      const float var  = s2 * (1.f / 128.f) - mean * mean;
      const float rstd = rsqrtf(var + LN_EPS);

      float* op = outg + ((size_t)b * LQ_ + q0 + row) * D_ + khalf * 64 + lr;
#pragma unroll
      for (int nb = 0; nb < 4; nb++)
        op[nb * 16] = (o[rt][nb][reg] - mean) * rstd * gam[nb] + bet[nb];
    }
}

extern "C" void kernel_launch(void* const* d_in, const int* in_sizes, int n_in,
                              void* d_out, int out_size, void* d_ws, size_t ws_size,
                              hipStream_t stream) {
  const float* q     = (const float*)d_in[0];
  const float* k     = (const float*)d_in[1];
  const float* v     = (const float*)d_in[2];
  const float* mask  = (const float*)d_in[3];
  const float* gamma = (const float*)d_in[4];
  const float* beta  = (const float*)d_in[5];
  float* out = (float*)d_out;

  unsigned short* khg = (unsigned short*)d_ws;
  unsigned short* klg = (unsigned short*)((char*)d_ws + KH_BYTES);
  unsigned int*   vtg = (unsigned int*)((char*)d_ws + VT_OFF);

  conv_kv<<<dim3(B_ * NTILE), dim3(256), 0, stream>>>(k, v, khg, klg, vtg);
  attn_ln_mfma<<<dim3(512), dim3(256), 0, stream>>>(q, mask, gamma, beta,
                                                    khg, klg, vtg, out);
}

// Round 4
// 192.002 us; speedup vs baseline: 1.2674x; 1.0232x over previous
//
#include <hip/hip_runtime.h>
#include <hip/hip_bf16.h>
#include <math.h>

#define LQ_  2048
#define LK_  2048
#define D_   128
#define B_   16
#define LN_EPS 1e-5f
#define TK_  32
#define NTILE (LK_ / TK_)

// Pre-converted tile images in workspace:
#define KH_TILE_US 4096          // 32 rows x 128 d ushort (8192 B)
#define VT_TILE_U  2048          // 128 d x 16 slot uint (8192 B)
#define KH_BYTES   ((size_t)B_ * NTILE * KH_TILE_US * 2)   // 8,388,608
#define VT_OFF     (2 * KH_BYTES)                           // 16,777,216
// total ws: 25,165,824 B

typedef __attribute__((ext_vector_type(8))) short short8;
typedef __attribute__((ext_vector_type(4))) float f32x4;

union FragU { uint4 u4; short8 s8; unsigned int u[4]; };

__device__ __forceinline__ unsigned int pk_bf16(float a, float b) {
  __hip_bfloat162 h = __float22bfloat162_rn(make_float2(a, b));
  unsigned int u;
  __builtin_memcpy(&u, &h, 4);
  return u;
}
__device__ __forceinline__ float bf_lo(unsigned int u){ unsigned int v = u << 16; float f; __builtin_memcpy(&f, &v, 4); return f; }
__device__ __forceinline__ float bf_hi(unsigned int u){ unsigned int v = u & 0xffff0000u; float f; __builtin_memcpy(&f, &v, 4); return f; }
__device__ __forceinline__ unsigned short bf16_bits(float x) {
  return (unsigned short)(pk_bf16(x, 0.f) & 0xffffu);
}

// K tiles: ushort [32 rows][128 d], 16B(8-ushort)-chunk XOR swizzle by row.
__device__ __forceinline__ int idxK(int row, int d) {
  return row * 128 + ((((d >> 3) ^ row) & 15) << 3) + (d & 7);
}
// Vt: uint [128 d][16 kp-slots]; 16B chunk g' = (g + (d>>1)) & 3.
__device__ __forceinline__ int idxVt(int d, int kp) {
  return d * 16 + ((((kp >> 2) + (d >> 1)) & 3) << 2) + (kp & 3);
}
// Ps: ushort [64 rows][32 cols], 8-ushort-chunk swizzle by quad bits of row.
// Wave w owns rows [w*16, w*16+16) -> fully wave-private.
__device__ __forceinline__ int idxPs(int row, int col) {
  return row * 32 + ((((col >> 3) ^ (row >> 2)) & 3) << 3) + (col & 7);
}

// Barrier that drains this wave's tile-stage DMA (stage ops are the oldest;
// the 8 newest vm ops -- prefetched mask loads -- stay in flight) and all ds.
__device__ __forceinline__ void barrier_stage() {
  asm volatile("s_waitcnt vmcnt(8) lgkmcnt(0)\n\ts_barrier" ::: "memory");
}
// Wave-local fence: Ps writes visible to this wave's own reads. No s_barrier.
__device__ __forceinline__ void fence_lds_local() {
  asm volatile("s_waitcnt lgkmcnt(0)" ::: "memory");
}

__device__ __forceinline__ void gld_lds16(const void* g, void* l) {
  __builtin_amdgcn_global_load_lds((const __attribute__((address_space(1))) void*)g,
                                   (__attribute__((address_space(3))) void*)l, 16, 0, 0);
}

// ---------------- pre-pass: K -> (Khi,Klo) bf16 swizzled, V -> bf16-pair Vt ----
__global__ __launch_bounds__(256) void conv_kv(
    const float* __restrict__ kg, const float* __restrict__ vg,
    unsigned short* __restrict__ khg, unsigned short* __restrict__ klg,
    unsigned int* __restrict__ vtg)
{
  __shared__ float Vlt[128 * 33];   // V tile transposed, +1-pad rows
  const int tid = threadIdx.x;
  const int blk = blockIdx.x;          // b*64 + t
  const int b = blk >> 6;
  const int t = blk & 63;

  const float* ks = kg + ((size_t)b * LK_ + t * 32) * D_;
  const float* vs = vg + ((size_t)b * LK_ + t * 32) * D_;
  unsigned short* kh = khg + (size_t)blk * KH_TILE_US;
  unsigned short* kl = klg + (size_t)blk * KH_TILE_US;
  unsigned int*   vt = vtg + (size_t)blk * VT_TILE_U;

  // K: 512 (row, 8-chunk) items, 2 per thread; coalesced reads, 16B swizzled writes
#pragma unroll
  for (int it = 0; it < 2; it++) {
    const int item = tid + it * 256;
    const int row = item >> 4;
    const int c8  = item & 15;
    const float* p = ks + row * D_ + c8 * 8;
    float4 x = *(const float4*)(p);
    float4 y = *(const float4*)(p + 4);
    FragU H, L;
    H.u[0] = pk_bf16(x.x, x.y); H.u[1] = pk_bf16(x.z, x.w);
    H.u[2] = pk_bf16(y.x, y.y); H.u[3] = pk_bf16(y.z, y.w);
    L.u[0] = pk_bf16(x.x - bf_lo(H.u[0]), x.y - bf_hi(H.u[0]));
    L.u[1] = pk_bf16(x.z - bf_lo(H.u[1]), x.w - bf_hi(H.u[1]));
    L.u[2] = pk_bf16(y.x - bf_lo(H.u[2]), y.y - bf_hi(H.u[2]));
    L.u[3] = pk_bf16(y.z - bf_lo(H.u[3]), y.w - bf_hi(H.u[3]));
    const int ik = idxK(row, c8 * 8);
    *(uint4*)&kh[ik] = H.u4;
    *(uint4*)&kl[ik] = L.u4;
  }

  // V tile -> LDS transposed (coalesced global reads).
#pragma unroll
  for (int i = 0; i < 4; i++) {
    const int item = tid + i * 256;
    const int r = item >> 5, c4 = item & 31;
    float4 x = *(const float4*)&vs[r * D_ + c4 * 4];
    Vlt[(c4 * 4 + 0) * 33 + r] = x.x;
    Vlt[(c4 * 4 + 1) * 33 + r] = x.y;
    Vlt[(c4 * 4 + 2) * 33 + r] = x.z;
    Vlt[(c4 * 4 + 3) * 33 + r] = x.w;
  }
  __syncthreads();

  // Emit Vt image linearly (coalesced writes); inverse-map slot -> kv pair.
#pragma unroll
  for (int i = 0; i < 8; i++) {
    const int o = tid + i * 256;
    const int d = o >> 4, s = o & 15;
    const int gq = s >> 2, c = s & 3;
    const int kp = (((gq - (d >> 1)) & 3) << 2) | c;
    vt[o] = pk_bf16(Vlt[d * 33 + 2 * kp], Vlt[d * 33 + 2 * kp + 1]);
  }
}

// ---------------- main fused attention + LN ----------------
// Stage one tile's images into LDS via global_load_lds: 6 x 1KiB/wave.
__device__ __forceinline__ void stage_tile(int w, int lane,
    const unsigned short* khT, const unsigned short* klT, const unsigned int* vtT,
    int tile, unsigned short* khs, unsigned short* kls, unsigned int* vts)
{
  const char* gkh = (const char*)(khT + (size_t)tile * KH_TILE_US);
  const char* gkl = (const char*)(klT + (size_t)tile * KH_TILE_US);
  const char* gvt = (const char*)(vtT + (size_t)tile * VT_TILE_U);
#pragma unroll
  for (int c = 0; c < 2; c++) {
    const int off = (w + 4 * c) << 10;            // 1 KiB chunks
    gld_lds16(gkh + off + lane * 16, (char*)khs + off);
    gld_lds16(gkl + off + lane * 16, (char*)kls + off);
    gld_lds16(gvt + off + lane * 16, (char*)vts + off);
  }
}

__global__ __launch_bounds__(256, 2) void attn_ln_mfma(
    const float* __restrict__ qg, const float* __restrict__ maskg,
    const float* __restrict__ gammag, const float* __restrict__ betag,
    const unsigned short* __restrict__ khg, const unsigned short* __restrict__ klg,
    const unsigned int* __restrict__ vtg,
    float* __restrict__ outg)
{
  __shared__ unsigned short KhS[2][32 * 128];   // 16 KB
  __shared__ unsigned short KlS[2][32 * 128];   // 16 KB
  __shared__ unsigned int   VtW[2][128 * 16];   // 16 KB
  __shared__ unsigned short PsS[64 * 32];       // 4 KB, wave-private 16-row bands
  // total 53,248 B

  const int tid  = threadIdx.x;
  const int w    = tid >> 6;     // wave owns q-rows [q0 + w*16, +16)
  const int lane = tid & 63;
  const int quad = lane >> 4;
  const int lr   = lane & 15;

  // XCD swizzle: blocks on XCD x serve batches {2x,2x+1} -> K/V L2-resident.
  const int id   = blockIdx.x;
  const int xcd  = id & 7;
  const int slot = id >> 3;
  const int b    = xcd * 2 + (slot >> 5);
  const int q0   = (slot & 31) * 64;

  const unsigned short* khT = khg + (size_t)b * NTILE * KH_TILE_US;
  const unsigned short* klT = klg + (size_t)b * NTILE * KH_TILE_US;
  const unsigned int*   vtT = vtg + (size_t)b * NTILE * VT_TILE_U;

  // mask rows for this lane: q0 + w*16 + quad*4 + reg
  const float* mbase = maskg + (size_t)(q0 + w * 16 + quad * 4) * LK_ + lr;

  // ---- issue tile-0 stage DMA + mask(0) prefetch (fly during Q-frag build) ----
  stage_tile(w, lane, khT, klT, vtT, 0, &KhS[0][0], &KlS[0][0], &VtW[0][0]);
  float mA[2][4], mB[2][4];
#pragma unroll
  for (int ct = 0; ct < 2; ct++)
#pragma unroll
    for (int reg = 0; reg < 4; reg++)
      mA[ct][reg] = mbase[(size_t)reg * LK_ + ct * 16];

  // ---- Q fragments (hi/lo) for this wave's 16 rows; row = w*16 + lr ----
  short8 qh[4], ql[4];
  {
    const float* qrow = qg + ((size_t)b * LQ_ + q0 + w * 16 + lr) * D_ + quad * 8;
#pragma unroll
    for (int c = 0; c < 4; c++) {
      float4 x = *(const float4*)(qrow + c * 32);
      float4 y = *(const float4*)(qrow + c * 32 + 4);
      FragU H, L;
      H.u[0] = pk_bf16(x.x, x.y); H.u[1] = pk_bf16(x.z, x.w);
      H.u[2] = pk_bf16(y.x, y.y); H.u[3] = pk_bf16(y.z, y.w);
      L.u[0] = pk_bf16(x.x - bf_lo(H.u[0]), x.y - bf_hi(H.u[0]));
      L.u[1] = pk_bf16(x.z - bf_lo(H.u[1]), x.w - bf_hi(H.u[1]));
      L.u[2] = pk_bf16(y.x - bf_lo(H.u[2]), y.y - bf_hi(H.u[2]));
      L.u[3] = pk_bf16(y.z - bf_lo(H.u[3]), y.w - bf_hi(H.u[3]));
      qh[c] = H.s8; ql[c] = L.s8;
    }
  }

  float l_part[4] = {0.f, 0.f, 0.f, 0.f};   // row = w*16 + quad*4 + reg
  f32x4 o[8];                               // [nb]: row = quad*4+reg, d = nb*16+lr
  const f32x4 zf = {0.f, 0.f, 0.f, 0.f};
#pragma unroll
  for (int n = 0; n < 8; n++) o[n] = zf;

  // One tile body. cur is a literal (0/1); mu holds mask(kt); mask(kt+1) is
  // prefetched into mp (named registers, no copies -> counted vmcnt at use).
  auto body = [&](int kt, int cur, float (&mu)[2][4], float (&mp)[2][4])
      __attribute__((always_inline)) -> void {
    const unsigned short* khc = &KhS[cur][0];
    const unsigned short* klc = &KlS[cur][0];
    const unsigned int*   vtc = &VtW[cur][0];

    // All waves past previous tile's LDS reads; this wave's stage(kt) done.
    barrier_stage();

    // ---- issue NEXT tile stage (6 vm) + NEXT mask prefetch (8 vm) ----
    if (kt + 1 < NTILE) {
      stage_tile(w, lane, khT, klT, vtT, kt + 1,
                 &KhS[cur ^ 1][0], &KlS[cur ^ 1][0], &VtW[cur ^ 1][0]);
#pragma unroll
      for (int ct = 0; ct < 2; ct++)
#pragma unroll
        for (int reg = 0; reg < 4; reg++)
          mp[ct][reg] = mbase[(size_t)reg * LK_ + (kt + 1) * TK_ + ct * 16];
    }

    // ---- S = Q K^T: this wave 16 rows x full 32 k-cols ----
    // 6 independent accumulator chains of length 4 for MFMA pipe fill.
    f32x4 sH[2], sL[2], sM[2];
    sH[0] = zf; sH[1] = zf; sL[0] = zf; sL[1] = zf; sM[0] = zf; sM[1] = zf;
#pragma unroll
    for (int c = 0; c < 4; c++) {
#pragma unroll
      for (int ct = 0; ct < 2; ct++) {
        const int ik = idxK(ct * 16 + lr, c * 32 + quad * 8);
        FragU kh, kl;
        kh.u4 = *(const uint4*)&khc[ik];
        kl.u4 = *(const uint4*)&klc[ik];
        sH[ct] = __builtin_amdgcn_mfma_f32_16x16x32_bf16(qh[c], kh.s8, sH[ct], 0, 0, 0);
        sL[ct] = __builtin_amdgcn_mfma_f32_16x16x32_bf16(ql[c], kh.s8, sL[ct], 0, 0, 0);
        sM[ct] = __builtin_amdgcn_mfma_f32_16x16x32_bf16(qh[c], kl.s8, sM[ct], 0, 0, 0);
      }
    }

    // ---- Bv reads issue early: LDS latency overlaps the exp chain ----
    FragU Bv[8];
#pragma unroll
    for (int nb = 0; nb < 8; nb++)
      Bv[nb].u4 = *(const uint4*)&vtc[idxVt(nb * 16 + lr, quad * 4)];

    // ---- max-free softmax; P -> wave-private Ps band as bf16 ----
    // sacc lane layout: q-row = quad*4+reg, k-col = ct*16+lr.
#pragma unroll
    for (int ct = 0; ct < 2; ct++)
#pragma unroll
      for (int reg = 0; reg < 4; reg++) {
        float s = sH[ct][reg] + sL[ct][reg] + sM[ct][reg];
        float p = __expf(s + mu[ct][reg]);
        l_part[reg] += p;
        PsS[idxPs(w * 16 + quad * 4 + reg, ct * 16 + lr)] = bf16_bits(p);
      }

    // Wave-local: own writes visible to own reads. NO cross-wave barrier.
    fence_lds_local();

    // ---- O += P * V: one A-frag (16 rows x 32 k), 8 MFMAs over d ----
    FragU A;
    A.u4 = *(const uint4*)&PsS[idxPs(w * 16 + lr, quad * 8)];
#pragma unroll
    for (int nb = 0; nb < 8; nb++)
      o[nb] = __builtin_amdgcn_mfma_f32_16x16x32_bf16(A.s8, Bv[nb].s8, o[nb], 0, 0, 0);
  };

  for (int kt = 0; kt < NTILE; kt += 2) {
    body(kt,     0, mA, mB);   // consumes mask in mA, prefetches into mB
    body(kt + 1, 1, mB, mA);   // consumes mask in mB, prefetches into mA
  }

  // ---- epilogue: fully wave-internal, zero barriers, zero LDS ----
  // l per row: sum over k lives across lr lanes (xor 1..8 stays in 16-group).
  float inv_l[4];
#pragma unroll
  for (int reg = 0; reg < 4; reg++) {
    float l = l_part[reg];
#pragma unroll
    for (int m = 1; m <= 8; m <<= 1) l += __shfl_xor(l, m, 64);
    inv_l[reg] = 1.f / l;
  }

  float gam[8], bet[8];
#pragma unroll
  for (int nb = 0; nb < 8; nb++) {
    gam[nb] = gammag[nb * 16 + lr];
    bet[nb] = betag[nb * 16 + lr];
  }

#pragma unroll
  for (int reg = 0; reg < 4; reg++) {
    float s1 = 0.f, s2 = 0.f;
#pragma unroll
    for (int nb = 0; nb < 8; nb++) {
      float v = o[nb][reg] * inv_l[reg];
      o[nb][reg] = v;
      s1 += v; s2 += v * v;
    }
#pragma unroll
    for (int m = 1; m <= 8; m <<= 1) {
      s1 += __shfl_xor(s1, m, 64);
      s2 += __shfl_xor(s2, m, 64);
    }
    const float mean = s1 * (1.f / 128.f);
    const float var  = s2 * (1.f / 128.f) - mean * mean;
    const float rstd = rsqrtf(var + LN_EPS);

    float* op = outg + ((size_t)b * LQ_ + q0 + w * 16 + quad * 4 + reg) * D_ + lr;
#pragma unroll
    for (int nb = 0; nb < 8; nb++)
      op[nb * 16] = (o[nb][reg] - mean) * rstd * gam[nb] + bet[nb];
  }
}

extern "C" void kernel_launch(void* const* d_in, const int* in_sizes, int n_in,
                              void* d_out, int out_size, void* d_ws, size_t ws_size,
                              hipStream_t stream) {
  const float* q     = (const float*)d_in[0];
  const float* k     = (const float*)d_in[1];
  const float* v     = (const float*)d_in[2];
  const float* mask  = (const float*)d_in[3];
  const float* gamma = (const float*)d_in[4];
  const float* beta  = (const float*)d_in[5];
  float* out = (float*)d_out;

  unsigned short* khg = (unsigned short*)d_ws;
  unsigned short* klg = (unsigned short*)((char*)d_ws + KH_BYTES);
  unsigned int*   vtg = (unsigned int*)((char*)d_ws + VT_OFF);

  conv_kv<<<dim3(B_ * NTILE), dim3(256), 0, stream>>>(k, v, khg, klg, vtg);
  attn_ln_mfma<<<dim3(512), dim3(256), 0, stream>>>(q, mask, gamma, beta,
                                                    khg, klg, vtg, out);
}

// Round 5
// 174.420 us; speedup vs baseline: 1.3952x; 1.1008x over previous
//
#include <hip/hip_runtime.h>
#include <hip/hip_bf16.h>
#include <hip/hip_fp16.h>
#include <math.h>

#define LQ_  2048
#define LK_  2048
#define D_   128
#define B_   16
#define LN_EPS 1e-5f
#define TK_  32
#define NTILE (LK_ / TK_)

// Pre-converted tile images in workspace:
#define KH_TILE_US 4096          // 32 rows x 128 d fp16 (8192 B)
#define VT_TILE_U  2048          // 128 d x 16 slot uint (8192 B)
#define KH_BYTES   ((size_t)B_ * NTILE * KH_TILE_US * 2)   // 8,388,608
#define VT_OFF     KH_BYTES                                 // 8,388,608
// total ws: 16,777,216 B

typedef __attribute__((ext_vector_type(8))) short short8;
typedef __attribute__((ext_vector_type(8))) _Float16 half8;
typedef __attribute__((ext_vector_type(4))) float f32x4;

union FragU { uint4 u4; short8 s8; half8 h8; unsigned int u[4]; };

__device__ __forceinline__ unsigned int pk_bf16(float a, float b) {
  __hip_bfloat162 h = __float22bfloat162_rn(make_float2(a, b));
  unsigned int u;
  __builtin_memcpy(&u, &h, 4);
  return u;
}
__device__ __forceinline__ unsigned short bf16_bits(float x) {
  return (unsigned short)(pk_bf16(x, 0.f) & 0xffffu);
}
__device__ __forceinline__ unsigned int pk_f16(float a, float b) {
  __half2 h = __floats2half2_rn(a, b);
  unsigned int u;
  __builtin_memcpy(&u, &h, 4);
  return u;
}
__device__ __forceinline__ float f16_lo(unsigned int u) {
  unsigned short s = (unsigned short)(u & 0xffffu);
  __half h; __builtin_memcpy(&h, &s, 2); return __half2float(h);
}
__device__ __forceinline__ float f16_hi(unsigned int u) {
  unsigned short s = (unsigned short)(u >> 16);
  __half h; __builtin_memcpy(&h, &s, 2); return __half2float(h);
}

// K tiles: ushort [32 rows][128 d], 16B(8-elem)-chunk XOR swizzle by row.
__device__ __forceinline__ int idxK(int row, int d) {
  return row * 128 + ((((d >> 3) ^ row) & 15) << 3) + (d & 7);
}
// Vt: uint [128 d][16 kp-slots]; 16B chunk g' = (g + (d>>1)) & 3.
__device__ __forceinline__ int idxVt(int d, int kp) {
  return d * 16 + ((((kp >> 2) + (d >> 1)) & 3) << 2) + (kp & 3);
}
// Ps: ushort [64 rows][32 cols], 8-ushort-chunk swizzle by quad bits of row.
// Wave w owns rows [w*16, w*16+16) -> fully wave-private.
__device__ __forceinline__ int idxPs(int row, int col) {
  return row * 32 + ((((col >> 3) ^ (row >> 2)) & 3) << 3) + (col & 7);
}

// Barrier that drains this wave's tile-stage DMA (stage ops are the oldest;
// the 8 newest vm ops -- prefetched mask loads -- stay in flight) and all ds.
__device__ __forceinline__ void barrier_stage() {
  asm volatile("s_waitcnt vmcnt(8) lgkmcnt(0)\n\ts_barrier" ::: "memory");
}
// Wave-local fence: Ps writes visible to this wave's own reads. No s_barrier.
__device__ __forceinline__ void fence_lds_local() {
  asm volatile("s_waitcnt lgkmcnt(0)" ::: "memory");
}

__device__ __forceinline__ void gld_lds16(const void* g, void* l) {
  __builtin_amdgcn_global_load_lds((const __attribute__((address_space(1))) void*)g,
                                   (__attribute__((address_space(3))) void*)l, 16, 0, 0);
}

// ---------------- pre-pass: K -> fp16 swizzled, V -> bf16-pair Vt ----------
__global__ __launch_bounds__(256) void conv_kv(
    const float* __restrict__ kg, const float* __restrict__ vg,
    unsigned short* __restrict__ khg, unsigned int* __restrict__ vtg)
{
  __shared__ float Vlt[128 * 33];   // V tile transposed, +1-pad rows
  const int tid = threadIdx.x;
  const int blk = blockIdx.x;          // b*64 + t
  const int b = blk >> 6;
  const int t = blk & 63;

  const float* ks = kg + ((size_t)b * LK_ + t * 32) * D_;
  const float* vs = vg + ((size_t)b * LK_ + t * 32) * D_;
  unsigned short* kh = khg + (size_t)blk * KH_TILE_US;
  unsigned int*   vt = vtg + (size_t)blk * VT_TILE_U;

  // K: 512 (row, 8-chunk) items, 2 per thread; coalesced reads, 16B swizzled writes
#pragma unroll
  for (int it = 0; it < 2; it++) {
    const int item = tid + it * 256;
    const int row = item >> 4;
    const int c8  = item & 15;
    const float* p = ks + row * D_ + c8 * 8;
    float4 x = *(const float4*)(p);
    float4 y = *(const float4*)(p + 4);
    FragU H;
    H.u[0] = pk_f16(x.x, x.y); H.u[1] = pk_f16(x.z, x.w);
    H.u[2] = pk_f16(y.x, y.y); H.u[3] = pk_f16(y.z, y.w);
    *(uint4*)&kh[idxK(row, c8 * 8)] = H.u4;
  }

  // V tile -> LDS transposed (coalesced global reads).
#pragma unroll
  for (int i = 0; i < 4; i++) {
    const int item = tid + i * 256;
    const int r = item >> 5, c4 = item & 31;
    float4 x = *(const float4*)&vs[r * D_ + c4 * 4];
    Vlt[(c4 * 4 + 0) * 33 + r] = x.x;
    Vlt[(c4 * 4 + 1) * 33 + r] = x.y;
    Vlt[(c4 * 4 + 2) * 33 + r] = x.z;
    Vlt[(c4 * 4 + 3) * 33 + r] = x.w;
  }
  __syncthreads();

  // Emit Vt image linearly (coalesced writes); inverse-map slot -> kv pair.
#pragma unroll
  for (int i = 0; i < 8; i++) {
    const int o = tid + i * 256;
    const int d = o >> 4, s = o & 15;
    const int gq = s >> 2, c = s & 3;
    const int kp = (((gq - (d >> 1)) & 3) << 2) | c;
    vt[o] = pk_bf16(Vlt[d * 33 + 2 * kp], Vlt[d * 33 + 2 * kp + 1]);
  }
}

// ---------------- main fused attention + LN ----------------
// Stage one tile's images into LDS via global_load_lds: 4 x 1KiB/wave.
__device__ __forceinline__ void stage_tile(int w, int lane,
    const unsigned short* khT, const unsigned int* vtT,
    int tile, unsigned short* khs, unsigned int* vts)
{
  const char* gkh = (const char*)(khT + (size_t)tile * KH_TILE_US);
  const char* gvt = (const char*)(vtT + (size_t)tile * VT_TILE_U);
#pragma unroll
  for (int c = 0; c < 2; c++) {
    const int off = (w + 4 * c) << 10;            // 1 KiB chunks
    gld_lds16(gkh + off + lane * 16, (char*)khs + off);
    gld_lds16(gvt + off + lane * 16, (char*)vts + off);
  }
}

__global__ __launch_bounds__(256, 2) void attn_ln_mfma(
    const float* __restrict__ qg, const float* __restrict__ maskg,
    const float* __restrict__ gammag, const float* __restrict__ betag,
    const unsigned short* __restrict__ khg, const unsigned int* __restrict__ vtg,
    float* __restrict__ outg)
{
  __shared__ unsigned short KhS[2][32 * 128];   // 16 KB (fp16)
  __shared__ unsigned int   VtW[2][128 * 16];   // 16 KB
  __shared__ unsigned short PsS[64 * 32];       // 4 KB, wave-private 16-row bands
  // total 36,864 B

  const int tid  = threadIdx.x;
  const int w    = tid >> 6;     // wave owns q-rows [q0 + w*16, +16)
  const int lane = tid & 63;
  const int quad = lane >> 4;
  const int lr   = lane & 15;

  // XCD swizzle: blocks on XCD x serve batches {2x,2x+1} -> K/V L2-resident.
  const int id   = blockIdx.x;
  const int xcd  = id & 7;
  const int slot = id >> 3;
  const int b    = xcd * 2 + (slot >> 5);
  const int q0   = (slot & 31) * 64;

  const unsigned short* khT = khg + (size_t)b * NTILE * KH_TILE_US;
  const unsigned int*   vtT = vtg + (size_t)b * NTILE * VT_TILE_U;

  // mask rows for this lane: q0 + w*16 + quad*4 + reg
  const float* mbase = maskg + (size_t)(q0 + w * 16 + quad * 4) * LK_ + lr;

  // ---- issue tile-0 stage DMA + mask(0) prefetch (fly during Q-frag build) ----
  stage_tile(w, lane, khT, vtT, 0, &KhS[0][0], &VtW[0][0]);
  float mA[2][4], mB[2][4];
#pragma unroll
  for (int ct = 0; ct < 2; ct++)
#pragma unroll
    for (int reg = 0; reg < 4; reg++)
      mA[ct][reg] = mbase[(size_t)reg * LK_ + ct * 16];

  // ---- Q fragments (fp16 hi/lo) for this wave's 16 rows; row = w*16 + lr ----
  half8 qh[4], ql[4];
  {
    const float* qrow = qg + ((size_t)b * LQ_ + q0 + w * 16 + lr) * D_ + quad * 8;
#pragma unroll
    for (int c = 0; c < 4; c++) {
      float4 x = *(const float4*)(qrow + c * 32);
      float4 y = *(const float4*)(qrow + c * 32 + 4);
      FragU H, L;
      H.u[0] = pk_f16(x.x, x.y); H.u[1] = pk_f16(x.z, x.w);
      H.u[2] = pk_f16(y.x, y.y); H.u[3] = pk_f16(y.z, y.w);
      L.u[0] = pk_f16(x.x - f16_lo(H.u[0]), x.y - f16_hi(H.u[0]));
      L.u[1] = pk_f16(x.z - f16_lo(H.u[1]), x.w - f16_hi(H.u[1]));
      L.u[2] = pk_f16(y.x - f16_lo(H.u[2]), y.y - f16_hi(H.u[2]));
      L.u[3] = pk_f16(y.z - f16_lo(H.u[3]), y.w - f16_hi(H.u[3]));
      qh[c] = H.h8; ql[c] = L.h8;
    }
  }

  float l_part[4] = {0.f, 0.f, 0.f, 0.f};   // row = w*16 + quad*4 + reg
  f32x4 o[8];                               // [nb]: row = quad*4+reg, d = nb*16+lr
  const f32x4 zf = {0.f, 0.f, 0.f, 0.f};
#pragma unroll
  for (int n = 0; n < 8; n++) o[n] = zf;

  // One tile body. cur is a literal (0/1); mu holds mask(kt); mask(kt+1) is
  // prefetched into mp (named registers, no copies -> counted vmcnt at use).
  auto body = [&](int kt, int cur, float (&mu)[2][4], float (&mp)[2][4])
      __attribute__((always_inline)) -> void {
    const unsigned short* khc = &KhS[cur][0];
    const unsigned int*   vtc = &VtW[cur][0];

    // All waves past previous tile's LDS reads; this wave's stage(kt) done.
    barrier_stage();

    // ---- issue NEXT tile stage (4 vm) + NEXT mask prefetch (8 vm) ----
    if (kt + 1 < NTILE) {
      stage_tile(w, lane, khT, vtT, kt + 1, &KhS[cur ^ 1][0], &VtW[cur ^ 1][0]);
#pragma unroll
      for (int ct = 0; ct < 2; ct++)
#pragma unroll
        for (int reg = 0; reg < 4; reg++)
          mp[ct][reg] = mbase[(size_t)reg * LK_ + (kt + 1) * TK_ + ct * 16];
    }

    // ---- S = Q K^T (fp16 2-term): 16 rows x full 32 k-cols ----
    // 4 independent accumulator chains of length 4.
    f32x4 sH[2], sL[2];
    sH[0] = zf; sH[1] = zf; sL[0] = zf; sL[1] = zf;
#pragma unroll
    for (int c = 0; c < 4; c++) {
#pragma unroll
      for (int ct = 0; ct < 2; ct++) {
        FragU kh;
        kh.u4 = *(const uint4*)&khc[idxK(ct * 16 + lr, c * 32 + quad * 8)];
        sH[ct] = __builtin_amdgcn_mfma_f32_16x16x32_f16(qh[c], kh.h8, sH[ct], 0, 0, 0);
        sL[ct] = __builtin_amdgcn_mfma_f32_16x16x32_f16(ql[c], kh.h8, sL[ct], 0, 0, 0);
      }
    }

    // ---- Bv reads issue early: LDS latency overlaps the exp chain ----
    FragU Bv[8];
#pragma unroll
    for (int nb = 0; nb < 8; nb++)
      Bv[nb].u4 = *(const uint4*)&vtc[idxVt(nb * 16 + lr, quad * 4)];

    // ---- max-free softmax; P -> wave-private Ps band as bf16 ----
    // sacc lane layout: q-row = quad*4+reg, k-col = ct*16+lr.
#pragma unroll
    for (int ct = 0; ct < 2; ct++)
#pragma unroll
      for (int reg = 0; reg < 4; reg++) {
        float s = sH[ct][reg] + sL[ct][reg];
        float p = __expf(s + mu[ct][reg]);
        l_part[reg] += p;
        PsS[idxPs(w * 16 + quad * 4 + reg, ct * 16 + lr)] = bf16_bits(p);
      }

    // Wave-local: own writes visible to own reads. NO cross-wave barrier.
    fence_lds_local();

    // ---- O += P * V: one A-frag (16 rows x 32 k), 8 MFMAs over d ----
    FragU A;
    A.u4 = *(const uint4*)&PsS[idxPs(w * 16 + lr, quad * 8)];
#pragma unroll
    for (int nb = 0; nb < 8; nb++)
      o[nb] = __builtin_amdgcn_mfma_f32_16x16x32_bf16(A.s8, Bv[nb].s8, o[nb], 0, 0, 0);
  };

  for (int kt = 0; kt < NTILE; kt += 2) {
    body(kt,     0, mA, mB);   // consumes mask in mA, prefetches into mB
    body(kt + 1, 1, mB, mA);   // consumes mask in mB, prefetches into mA
  }

  // ---- epilogue: fully wave-internal, zero barriers, zero LDS ----
  float inv_l[4];
#pragma unroll
  for (int reg = 0; reg < 4; reg++) {
    float l = l_part[reg];
#pragma unroll
    for (int m = 1; m <= 8; m <<= 1) l += __shfl_xor(l, m, 64);
    inv_l[reg] = 1.f / l;
  }

  float gam[8], bet[8];
#pragma unroll
  for (int nb = 0; nb < 8; nb++) {
    gam[nb] = gammag[nb * 16 + lr];
    bet[nb] = betag[nb * 16 + lr];
  }

#pragma unroll
  for (int reg = 0; reg < 4; reg++) {
    float s1 = 0.f, s2 = 0.f;
#pragma unroll
    for (int nb = 0; nb < 8; nb++) {
      float v = o[nb][reg] * inv_l[reg];
      o[nb][reg] = v;
      s1 += v; s2 += v * v;
    }
#pragma unroll
    for (int m = 1; m <= 8; m <<= 1) {
      s1 += __shfl_xor(s1, m, 64);
      s2 += __shfl_xor(s2, m, 64);
    }
    const float mean = s1 * (1.f / 128.f);
    const float var  = s2 * (1.f / 128.f) - mean * mean;
    const float rstd = rsqrtf(var + LN_EPS);

    float* op = outg + ((size_t)b * LQ_ + q0 + w * 16 + quad * 4 + reg) * D_ + lr;
#pragma unroll
    for (int nb = 0; nb < 8; nb++)
      op[nb * 16] = (o[nb][reg] - mean) * rstd * gam[nb] + bet[nb];
  }
}

extern "C" void kernel_launch(void* const* d_in, const int* in_sizes, int n_in,
                              void* d_out, int out_size, void* d_ws, size_t ws_size,
                              hipStream_t stream) {
  const float* q     = (const float*)d_in[0];
  const float* k     = (const float*)d_in[1];
  const float* v     = (const float*)d_in[2];
  const float* mask  = (const float*)d_in[3];
  const float* gamma = (const float*)d_in[4];
  const float* beta  = (const float*)d_in[5];
  float* out = (float*)d_out;

  unsigned short* khg = (unsigned short*)d_ws;
  unsigned int*   vtg = (unsigned int*)((char*)d_ws + VT_OFF);

  conv_kv<<<dim3(B_ * NTILE), dim3(256), 0, stream>>>(k, v, khg, vtg);
  attn_ln_mfma<<<dim3(512), dim3(256), 0, stream>>>(q, mask, gamma, beta,
                                                    khg, vtg, out);
}